// Round 1
// baseline (2701.396 us; speedup 1.0000x reference)
//
#include <hip/hip_runtime.h>
#include <stdint.h>

// Autoregressive LSTM, B=256, H=1024, T=128.
// Key ideas:
//  - x==h for steps >=2  => combined weights W = Wi+Wh (4 GEMMs/step, not 8)
//  - combined bf16 weights (8MB) live persistently in LDS (128KB per WG, 256 WGs)
//  - one persistent kernel; 1 WG/CU guaranteed by LDS size; c-state in registers
//  - cross-step h exchange: bf16 shadow at FRESH addresses each step (no stale
//    cache lines possible), written with agent-scope atomic stores; per-64-col
//    flag counters (4 producers each) consumed in diagonal order with deep
//    prefetch so sync latency hides under MFMA work.

#define BATCH 256
#define HID   1024

typedef __bf16 bf16_t;
typedef bf16_t bf16x8 __attribute__((ext_vector_type(8)));
typedef float  f32x16 __attribute__((ext_vector_type(16)));
typedef float  f32x4  __attribute__((ext_vector_type(4)));
typedef unsigned int u32;
typedef unsigned long long u64;

// ---- workspace layout (bytes) ----
// [0, 64MB)   : h shadow bf16 [T][256][1024]  (Wi overlaid on tail, steps T-16..T-1)
// [64MB,72MB) : combined weights Wc bf16 [4096][1024], row = j*4 + gate
// [72MB, +16K): combined bias f32 [4096]
// [72MB+64K)  : flags u32 [T][4][16]
#define WC_OFF    (64ull << 20)
#define BIAS_OFF  (72ull << 20)
#define FLAG_OFF  ((72ull << 20) + (1ull << 16))

// LDS: [0,131072) weights (64 rows x 1024 bf16, XOR-swizzled)
//      [131072, +16384) preact exchange [64][64] f32 (XOR-swizzled)
//      [147456, +256)  bias slice
#define LDS_BYTES 147712

__global__ __launch_bounds__(256) void k_prep(
    const float* __restrict__ wf, const float* __restrict__ wi_,
    const float* __restrict__ wo, const float* __restrict__ wc,
    const float* __restrict__ hf, const float* __restrict__ hi,
    const float* __restrict__ ho, const float* __restrict__ hc,
    const float* __restrict__ bf_, const float* __restrict__ bi_,
    const float* __restrict__ bo_, const float* __restrict__ bc_,
    const float* __restrict__ hbf, const float* __restrict__ hbi,
    const float* __restrict__ hbo, const float* __restrict__ hbc,
    bf16_t* __restrict__ Wc, bf16_t* __restrict__ Wi, float* __restrict__ bias)
{
  int r = blockIdx.x;            // 0..4095, row = j*4 + g  (gate order f,i,o,c)
  int j = r >> 2, g = r & 3;
  const float *wip, *whp, *bip, *bhp;
  switch (g) {
    case 0:  wip = wf;  whp = hf; bip = bf_; bhp = hbf; break;
    case 1:  wip = wi_; whp = hi; bip = bi_; bhp = hbi; break;
    case 2:  wip = wo;  whp = ho; bip = bo_; bhp = hbo; break;
    default: wip = wc;  whp = hc; bip = bc_; bhp = hbc; break;
  }
  int k = threadIdx.x * 4;
  f32x4 a = *(const f32x4*)(wip + (size_t)j * HID + k);
  f32x4 b = *(const f32x4*)(whp + (size_t)j * HID + k);
  union { bf16_t h[4]; u64 v; } pc, pi;
#pragma unroll
  for (int t = 0; t < 4; ++t) { pc.h[t] = (bf16_t)(a[t] + b[t]); pi.h[t] = (bf16_t)a[t]; }
  *(u64*)(Wc + (size_t)r * HID + k) = pc.v;
  *(u64*)(Wi + (size_t)r * HID + k) = pi.v;
  if (threadIdx.x == 0) bias[r] = bip[j] + bhp[j];
}

__global__ __launch_bounds__(256) void k_init(
    const float* __restrict__ x0, float* __restrict__ out,
    bf16_t* __restrict__ hsh, u32* __restrict__ flags, int nflags)
{
  int gid = blockIdx.x * 256 + threadIdx.x;   // 65536 threads x 4 elems
  int i = gid * 4;
  f32x4 v = *(const f32x4*)(x0 + i);
  __builtin_nontemporal_store(v, (f32x4*)(out + i));
  union { bf16_t h[4]; u64 u; } p;
#pragma unroll
  for (int t = 0; t < 4; ++t) p.h[t] = (bf16_t)v[t];
  *(u64*)(hsh + i) = p.u;
  if (gid < nflags) flags[gid] = 0;
}

__global__ __launch_bounds__(256, 1) void k_lstm(
    const bf16_t* __restrict__ Wc, const bf16_t* __restrict__ Wi,
    const float* __restrict__ bias, bf16_t* __restrict__ hsh,
    u32* __restrict__ flags, float* __restrict__ out, int T)
{
  extern __shared__ char lds[];
  float* plds = (float*)(lds + 131072);
  float* blds = (float*)(lds + 131072 + 16384);

  const int tid  = threadIdx.x;
  const int bid  = blockIdx.x;
  // XCD clustering: xcd = bid%8 -> mt constant per XCD pair (A-slice L2 locality)
  const int mt   = (bid >> 1) & 3;                 // M-group 0..3 (64 batch rows)
  const int jt   = ((bid >> 3) << 1) | (bid & 1);  // 0..63 (16 hidden cols)
  const int lane = tid & 63;
  const int wave = tid >> 6;
  const int wm = (wave >> 1) & 1, wn = wave & 1;   // 2x2 waves of 32x32 tiles
  const int al = lane & 31, kh = lane >> 5;
  const int row0 = jt << 6;                        // weight row base (64 rows)

  // ---- stage weights into LDS (XOR-swizzled rows) ----
  for (int idx = tid; idx < 8192; idx += 256) {    // 16B chunks: 64 rows x 128
    int r = idx >> 7, k16 = idx & 127;
    int4 v = *(const int4*)(Wc + ((size_t)(row0 + r) << 10) + (k16 << 3));
    *(int4*)(lds + r * 2048 + ((k16 << 4) ^ ((r & 7) << 4))) = v;
  }
  if (tid < 64) blds[tid] = bias[row0 + tid];
  __syncthreads();

  const int arow   = (mt << 6) + (wm << 5) + al;   // global A (batch) row
  const int brow_g = row0 + (wn << 5) + al;        // global B row (step 1 only)
  const int brow_l = (wn << 5) + al;               // LDS B row
  const int bswz   = (brow_l & 7) << 4;
  const char* bbase = lds + brow_l * 2048;

  const int bloc = tid >> 2;                       // epilogue: local batch row
  const int j4   = (tid & 3) << 2;                 // epilogue: local j base
  const int bg   = (mt << 6) + bloc;
  const int jg   = (jt << 4) + j4;

  float cst[4] = {0.f, 0.f, 0.f, 0.f};             // c-state, lives in VGPRs

  for (int s = 1; s < T; ++s) {
    const bf16_t* hp = hsh + ((size_t)(s - 1) << 18);
    const u32* fl = flags + ((size_t)(s - 1) << 6) + (mt << 4);
    const int g0 = jt >> 2;                        // start K-walk at own columns
    f32x16 acc = {};

    u32 fv[8];
    if (s >= 2) {
#pragma unroll
      for (int i = 0; i < 8; ++i)
        fv[i] = __hip_atomic_load(fl + ((g0 + i) & 15), __ATOMIC_RELAXED,
                                  __HIP_MEMORY_SCOPE_AGENT);
    }
#pragma unroll 8
    for (int gi = 0; gi < 16; ++gi) {
      const int grp = (g0 + gi) & 15;              // 64-k group
      if (s >= 2) {
        u32 v = fv[gi & 7];
        if (v < 4) {                               // straggler: spin (bounded)
          const u32* fp = fl + grp;
          int guard = 0;
          while (v < 4 && guard < 4096) {
            __builtin_amdgcn_s_sleep(2);
            v = __hip_atomic_load(fp, __ATOMIC_RELAXED, __HIP_MEMORY_SCOPE_AGENT);
            ++guard;
          }
        }
        fv[gi & 7] = __hip_atomic_load(fl + ((g0 + gi + 8) & 15), __ATOMIC_RELAXED,
                                       __HIP_MEMORY_SCOPE_AGENT);
      }
      const int kb = grp << 6;
      if (s == 1) {                                // B = Wi from global (h==0 step)
#pragma unroll
        for (int cc = 0; cc < 4; ++cc) {
          int k = kb + (cc << 4) + (kh << 3);
          bf16x8 af  = *(const bf16x8*)(hp + ((size_t)arow << 10) + k);
          bf16x8 bfr = *(const bf16x8*)(Wi + ((size_t)brow_g << 10) + k);
          acc = __builtin_amdgcn_mfma_f32_32x32x16_bf16(af, bfr, acc, 0, 0, 0);
        }
      } else {                                     // B = combined weights from LDS
#pragma unroll
        for (int cc = 0; cc < 4; ++cc) {
          int k = kb + (cc << 4) + (kh << 3);
          bf16x8 af  = *(const bf16x8*)(hp + ((size_t)arow << 10) + k);
          bf16x8 bfr = *(const bf16x8*)(bbase + ((k << 1) ^ bswz));
          acc = __builtin_amdgcn_mfma_f32_32x32x16_bf16(af, bfr, acc, 0, 0, 0);
        }
      }
    }

    // ---- epilogue: exchange preacts through LDS, gate math, emit h ----
#pragma unroll
    for (int r = 0; r < 16; ++r) {
      int prow = (wm << 5) + (r & 3) + ((r >> 2) << 3) + (kh << 2);
      int pcol = (wn << 5) + al;
      *(float*)((char*)plds + prow * 256 + (((pcol << 2)) ^ ((prow & 7) << 4))) = acc[r];
    }
    __syncthreads();

    float hq[4];
#pragma unroll
    for (int q = 0; q < 4; ++q) {
      int nc = (j4 + q) << 2;                      // 4 gates of one (b,j)
      f32x4 p  = *(const f32x4*)((char*)plds + bloc * 256 + (((nc << 2)) ^ ((bloc & 7) << 4)));
      f32x4 bb = *(const f32x4*)(blds + nc);
      float xf = p[0] + bb[0], xi = p[1] + bb[1], xo = p[2] + bb[2], xc = p[3] + bb[3];
      float gf = 1.f / (1.f + __expf(-xf));
      float gi = 1.f / (1.f + __expf(-xi));
      float go = 1.f / (1.f + __expf(-xo));
      float cp = tanhf(xc);
      cst[q] = gf * cst[q] + gi * cp;
      hq[q]  = go * tanhf(cst[q]);
    }
    union { bf16_t h[4]; u64 v; } pk;
#pragma unroll
    for (int q = 0; q < 4; ++q) pk.h[q] = (bf16_t)hq[q];
    // h shadow: fresh address every step + agent-scope store => never stale
    __hip_atomic_store((u64*)(hsh + ((size_t)s << 18) + ((size_t)bg << 10) + jg), pk.v,
                       __ATOMIC_RELAXED, __HIP_MEMORY_SCOPE_AGENT);
    f32x4 ov; ov[0] = hq[0]; ov[1] = hq[1]; ov[2] = hq[2]; ov[3] = hq[3];
    __builtin_nontemporal_store(ov, (f32x4*)(out + ((size_t)s << 18) + ((size_t)bg << 10) + jg));

    asm volatile("s_waitcnt vmcnt(0)" ::: "memory"); // all stores acked at L3
    __syncthreads();                                 // whole WG done
    if (tid == 0)
      __hip_atomic_fetch_add(flags + ((size_t)s << 6) + (mt << 4) + (jt >> 2), 1u,
                             __ATOMIC_RELAXED, __HIP_MEMORY_SCOPE_AGENT);
  }
}

extern "C" void kernel_launch(void* const* d_in, const int* in_sizes, int n_in,
                              void* d_out, int out_size, void* d_ws, size_t ws_size,
                              hipStream_t stream) {
  const float* Wif = (const float*)d_in[0];
  const float* bif = (const float*)d_in[1];
  const float* Wii = (const float*)d_in[2];
  const float* bii = (const float*)d_in[3];
  const float* Wio = (const float*)d_in[4];
  const float* bio = (const float*)d_in[5];
  const float* Wic = (const float*)d_in[6];
  const float* bic = (const float*)d_in[7];
  const float* Whf = (const float*)d_in[8];
  const float* bhf = (const float*)d_in[9];
  const float* Whi = (const float*)d_in[10];
  const float* bhi = (const float*)d_in[11];
  const float* Who = (const float*)d_in[12];
  const float* bho = (const float*)d_in[13];
  const float* Whc = (const float*)d_in[14];
  const float* bhc = (const float*)d_in[15];
  const float* x0  = (const float*)d_in[16];
  const int T = out_size / (BATCH * HID);          // 128

  char* ws = (char*)d_ws;
  bf16_t* hsh  = (bf16_t*)ws;
  bf16_t* WcP  = (bf16_t*)(ws + WC_OFF);
  // Wi (step-1 weights) overlaid on h-shadow tail (steps T-16..T-1): only read
  // during step 1, overwritten ~100 steps later.
  bf16_t* WiP  = hsh + ((size_t)(T - 16) << 18);
  float*  bias = (float*)(ws + BIAS_OFF);
  u32*    flg  = (u32*)(ws + FLAG_OFF);
  float*  out  = (float*)d_out;

  hipFuncSetAttribute((const void*)k_lstm,
                      hipFuncAttributeMaxDynamicSharedMemorySize, LDS_BYTES);

  k_prep<<<4096, 256, 0, stream>>>(Wif, Wii, Wio, Wic, Whf, Whi, Who, Whc,
                                   bif, bii, bio, bic, bhf, bhi, bho, bhc,
                                   WcP, WiP, bias);
  k_init<<<256, 256, 0, stream>>>(x0, out, hsh, flg, T * 64);
  k_lstm<<<256, 256, LDS_BYTES, stream>>>(WcP, WiP, bias, hsh, flg, out, T);
}

// Round 3
// 736.693 us; speedup vs baseline: 3.6669x; 3.6669x over previous
//
#include <hip/hip_runtime.h>
#include <stdint.h>

// Autoregressive LSTM, B=256, H=1024, T=128.
//  - x==h for steps >=2  => combined weights W = Wi+Wh (4 GEMMs/step)
//  - weights persistent in REGISTERS (B-frags, 128 VGPR/wave); no weight LDS
//  - A (=h[s-1]) staged into LDS per step via global_load_lds (swizzled)
//  - WG = 32 batch rows x 128 gate cols; mt=bid&7 => recurrence is XCD-local
//  - 8 waves: 2 col-halves x 4-way K-split; partials reduced through LDS
//  - sync: 1 flag store per WG per step; wave0 polls 32 flags lane-parallel

#define BATCH 256
#define HID   1024

typedef __bf16 bf16_t;
typedef bf16_t bf16x8 __attribute__((ext_vector_type(8)));
typedef float  f32x16 __attribute__((ext_vector_type(16)));
typedef float  f32x4  __attribute__((ext_vector_type(4)));
typedef float  f32x2  __attribute__((ext_vector_type(2)));
typedef unsigned int u32;
typedef unsigned long long u64;

// ---- workspace layout (bytes) ----
// [0, 64MB)   : h shadow bf16 [T][256][1024]  (Wi overlaid on tail, steps T-16..T-1)
// [64MB,72MB) : combined weights Wc bf16 [4096][1024], row = j*4 + gate
// [72MB,+16K) : combined bias f32 [4096]
// [72MB+64K)  : flags u32 [T][8][32]
#define WC_OFF    (64ull << 20)
#define BIAS_OFF  (72ull << 20)
#define FLAG_OFF  ((72ull << 20) + (1ull << 16))

// LDS: [0,65536) A region (32 rows x 2048B, XOR-swizzled), reused for K-split
//      partials [4][32][128] f32 after compute; [65536,+512) bias slice.
#define LDS_BYTES 98304   // padded to force 1 WG/CU

__device__ __forceinline__ void gload_lds16(const void* g, void* l) {
  auto gp = reinterpret_cast<const __attribute__((address_space(1))) unsigned int*>(
      reinterpret_cast<uintptr_t>(g));
  auto lp = reinterpret_cast<__attribute__((address_space(3))) unsigned int*>(
      reinterpret_cast<uintptr_t>(l));
  __builtin_amdgcn_global_load_lds(gp, lp, 16, 0, 0);
}

__global__ __launch_bounds__(256) void k_prep(
    const float* __restrict__ wf, const float* __restrict__ wi_,
    const float* __restrict__ wo, const float* __restrict__ wc,
    const float* __restrict__ hf, const float* __restrict__ hi,
    const float* __restrict__ ho, const float* __restrict__ hc,
    const float* __restrict__ bf_, const float* __restrict__ bi_,
    const float* __restrict__ bo_, const float* __restrict__ bc_,
    const float* __restrict__ hbf, const float* __restrict__ hbi,
    const float* __restrict__ hbo, const float* __restrict__ hbc,
    bf16_t* __restrict__ Wc, bf16_t* __restrict__ Wi, float* __restrict__ bias)
{
  int r = blockIdx.x;            // 0..4095, row = j*4 + g  (gate order f,i,o,c)
  int j = r >> 2, g = r & 3;
  const float *wip, *whp, *bip, *bhp;
  switch (g) {
    case 0:  wip = wf;  whp = hf; bip = bf_; bhp = hbf; break;
    case 1:  wip = wi_; whp = hi; bip = bi_; bhp = hbi; break;
    case 2:  wip = wo;  whp = ho; bip = bo_; bhp = hbo; break;
    default: wip = wc;  whp = hc; bip = bc_; bhp = hbc; break;
  }
  int k = threadIdx.x * 4;
  f32x4 a = *(const f32x4*)(wip + (size_t)j * HID + k);
  f32x4 b = *(const f32x4*)(whp + (size_t)j * HID + k);
  union { bf16_t h[4]; u64 v; } pc, pi;
#pragma unroll
  for (int t = 0; t < 4; ++t) { pc.h[t] = (bf16_t)(a[t] + b[t]); pi.h[t] = (bf16_t)a[t]; }
  *(u64*)(Wc + (size_t)r * HID + k) = pc.v;
  *(u64*)(Wi + (size_t)r * HID + k) = pi.v;
  if (threadIdx.x == 0) bias[r] = bip[j] + bhp[j];
}

__global__ __launch_bounds__(256) void k_init(
    const float* __restrict__ x0, float* __restrict__ out,
    bf16_t* __restrict__ hsh, u32* __restrict__ flags, int nflags)
{
  int gid = blockIdx.x * 256 + threadIdx.x;   // 65536 threads x 4 elems
  int i = gid * 4;
  f32x4 v = *(const f32x4*)(x0 + i);
  __builtin_nontemporal_store(v, (f32x4*)(out + i));
  union { bf16_t h[4]; u64 u; } p;
#pragma unroll
  for (int t = 0; t < 4; ++t) p.h[t] = (bf16_t)v[t];
  *(u64*)(hsh + i) = p.u;
  if (gid < nflags) flags[gid] = 0;
}

__global__ __launch_bounds__(512, 2) void k_lstm(
    const bf16_t* __restrict__ Wc, const bf16_t* __restrict__ Wi,
    const float* __restrict__ bias, bf16_t* __restrict__ hsh,
    u32* __restrict__ flags, float* __restrict__ out, int T)
{
  extern __shared__ char lds[];
  float* blds = (float*)(lds + 65536);

  const int tid  = threadIdx.x;
  const int bid  = blockIdx.x;
  const int mt   = bid & 7;          // XCD id == batch group (32 rows): local L2
  const int jt   = bid >> 3;         // 0..31: 32 hidden cols / 128 gate rows
  const int lane = tid & 63;
  const int wv   = tid >> 6;         // 0..7
  const int wn   = wv & 1;           // col half (2 tiles of 32 gate cols each)
  const int ks   = wv >> 1;          // k quarter (256 of 1024)
  const int al   = lane & 31, kh = lane >> 5;
  const int row0 = jt << 7;          // first gate row of this WG

  if (tid < 128) blds[tid] = bias[row0 + tid];

  // epilogue mapping: thread -> (batch row eb, hidden col pair jp)
  const int eb   = tid >> 4;         // 0..31
  const int jp   = (tid & 15) << 1;  // 0,2,..,30
  const int bswz = (eb & 7) << 4;
  float cst0 = 0.f, cst1 = 0.f;      // c-state (2 cells/thread), in VGPRs

  const int aswz = (al & 7) << 4;
  bf16x8 breg0[16], breg1[16];       // persistent B fragments (128 VGPRs)

  for (int s = 1; s < T; ++s) {
    // ---- wait until all 32 producers of h[s-1] (same XCD) flagged ----
    if (s >= 2 && wv == 0) {
      const u32* f = flags + ((size_t)(s - 1) << 8) + (mt << 5);
      u32 v = (lane < 32) ? 0u : 1u;
      if (lane < 32)
        v = __hip_atomic_load(f + lane, __ATOMIC_RELAXED, __HIP_MEMORY_SCOPE_AGENT);
      int guard = 0;
      while (!__all(v != 0) && guard < (1 << 20)) {
        __builtin_amdgcn_s_sleep(1);
        if (lane < 32 && v == 0)
          v = __hip_atomic_load(f + lane, __ATOMIC_RELAXED, __HIP_MEMORY_SCOPE_AGENT);
        ++guard;
      }
    }
    __syncthreads();

    // ---- stage h[s-1] slice (32 rows x 1024 bf16 = 64KB) into LDS ----
    // linear LDS dest (global_load_lds requirement), pre-swizzled global src
    {
      const char* hp = (const char*)hsh + ((size_t)(s - 1) << 19) + ((size_t)mt << 16);
#pragma unroll
      for (int c = 0; c < 8; ++c) {
        int d = (c << 13) + (tid << 4);
        int row = d >> 11, off = d & 2047;
        gload_lds16(hp + row * 2048 + (off ^ ((row & 7) << 4)), lds + d);
      }
    }
    if (s <= 2) {  // load B-frags: step 1 = Wi (h==0), step 2 = combined Wc
      const bf16_t* WB  = (s == 1) ? Wi : Wc;
      const bf16_t* wb0 = WB + ((size_t)(row0 + (wn << 6) + al) << 10) + (ks << 8) + (kh << 3);
      const bf16_t* wb1 = wb0 + (32 << 10);
#pragma unroll
      for (int kk = 0; kk < 16; ++kk) {
        breg0[kk] = *(const bf16x8*)(wb0 + (kk << 4));
        breg1[kk] = *(const bf16x8*)(wb1 + (kk << 4));
      }
    }
    asm volatile("s_waitcnt vmcnt(0)" ::: "memory");
    __syncthreads();

    // ---- MFMA: 2 col-tiles per A-fragment read, K-range 256 per wave ----
    f32x16 acc0 = {}, acc1 = {};
    {
      const char* abase = lds + al * 2048;
      const int kb0 = (ks << 9) + (kh << 4);
#pragma unroll
      for (int kk = 0; kk < 16; ++kk) {
        bf16x8 a = *(const bf16x8*)(abase + ((kb0 + (kk << 5)) ^ aswz));
        acc0 = __builtin_amdgcn_mfma_f32_32x32x16_bf16(a, breg0[kk], acc0, 0, 0, 0);
        acc1 = __builtin_amdgcn_mfma_f32_32x32x16_bf16(a, breg1[kk], acc1, 0, 0, 0);
      }
    }
    __syncthreads();   // all A reads done; partials reuse the A region

    // ---- write K-split partials [ks][32][128] f32 (swizzled rows) ----
#pragma unroll
    for (int r = 0; r < 16; ++r) {
      int prow = (r & 3) + ((r >> 2) << 3) + (kh << 2);
      char* pb = lds + (ks << 14) + prow * 512;
      int sw = (prow & 7) << 4;
      *(float*)(pb + ((((wn << 6) + al) << 2) ^ sw))      = acc0[r];
      *(float*)(pb + ((((wn << 6) + 32 + al) << 2) ^ sw)) = acc1[r];
    }
    __syncthreads();

    // ---- epilogue: reduce 4 partials, gate math, emit h ----
    float hv[2];
#pragma unroll
    for (int e = 0; e < 2; ++e) {
      int cb = (jp + e) << 4;        // gate-quad byte offset
      int co = cb ^ bswz;
      const char* pb = lds + eb * 512;
      f32x4 p = *(const f32x4*)(pb + co);
      p += *(const f32x4*)(pb + 16384 + co);
      p += *(const f32x4*)(pb + 32768 + co);
      p += *(const f32x4*)(pb + 49152 + co);
      f32x4 bb = *(const f32x4*)((const char*)blds + cb);
      float xf = p[0] + bb[0], xi = p[1] + bb[1], xo = p[2] + bb[2], xc = p[3] + bb[3];
      float gf = 1.f / (1.f + __expf(-xf));
      float gi = 1.f / (1.f + __expf(-xi));
      float go = 1.f / (1.f + __expf(-xo));
      float cp = tanhf(xc);
      float &cs = e ? cst1 : cst0;
      cs = gf * cs + gi * cp;
      hv[e] = go * tanhf(cs);
    }
    union { bf16_t h2[2]; u32 u; } pk;
    pk.h2[0] = (bf16_t)hv[0]; pk.h2[1] = (bf16_t)hv[1];
    size_t eoff = ((size_t)s << 18) + ((size_t)((mt << 5) + eb) << 10) + (jt << 5) + jp;
    // fresh address every step + agent-scope store => never stale anywhere
    __hip_atomic_store((u32*)(hsh + eoff), pk.u, __ATOMIC_RELAXED, __HIP_MEMORY_SCOPE_AGENT);
    f32x2 ov; ov[0] = hv[0]; ov[1] = hv[1];
    __builtin_nontemporal_store(ov, (f32x2*)(out + eoff));

    asm volatile("s_waitcnt vmcnt(0)" ::: "memory"); // h stores at coherence point
    __syncthreads();                                 // whole WG drained
    if (tid == 0)
      __hip_atomic_store(flags + ((size_t)s << 8) + (mt << 5) + jt, 1u,
                         __ATOMIC_RELAXED, __HIP_MEMORY_SCOPE_AGENT);
  }
}

extern "C" void kernel_launch(void* const* d_in, const int* in_sizes, int n_in,
                              void* d_out, int out_size, void* d_ws, size_t ws_size,
                              hipStream_t stream) {
  const float* Wif = (const float*)d_in[0];
  const float* bif = (const float*)d_in[1];
  const float* Wii = (const float*)d_in[2];
  const float* bii = (const float*)d_in[3];
  const float* Wio = (const float*)d_in[4];
  const float* bio = (const float*)d_in[5];
  const float* Wic = (const float*)d_in[6];
  const float* bic = (const float*)d_in[7];
  const float* Whf = (const float*)d_in[8];
  const float* bhf = (const float*)d_in[9];
  const float* Whi = (const float*)d_in[10];
  const float* bhi = (const float*)d_in[11];
  const float* Who = (const float*)d_in[12];
  const float* bho = (const float*)d_in[13];
  const float* Whc = (const float*)d_in[14];
  const float* bhc = (const float*)d_in[15];
  const float* x0  = (const float*)d_in[16];
  const int T = out_size / (BATCH * HID);          // 128

  char* ws = (char*)d_ws;
  bf16_t* hsh  = (bf16_t*)ws;
  bf16_t* WcP  = (bf16_t*)(ws + WC_OFF);
  // Wi (step-1 weights) overlaid on h-shadow tail (steps T-16..T-1): only read
  // during step 1's B-load, overwritten ~100 steps later.
  bf16_t* WiP  = hsh + ((size_t)(T - 16) << 18);
  float*  bias = (float*)(ws + BIAS_OFF);
  u32*    flg  = (u32*)(ws + FLAG_OFF);
  float*  out  = (float*)d_out;

  hipFuncSetAttribute((const void*)k_lstm,
                      hipFuncAttributeMaxDynamicSharedMemorySize, LDS_BYTES);

  k_prep<<<4096, 256, 0, stream>>>(Wif, Wii, Wio, Wic, Whf, Whi, Who, Whc,
                                   bif, bii, bio, bic, bhf, bhi, bho, bhc,
                                   WcP, WiP, bias);
  k_init<<<256, 256, 0, stream>>>(x0, out, hsh, flg, T * 256);
  k_lstm<<<256, 512, LDS_BYTES, stream>>>(WcP, WiP, bias, hsh, flg, out, T);
}